// Round 12
// 347.592 us; speedup vs baseline: 3.3879x; 1.0136x over previous
//
#include <hip/hip_runtime.h>

// ---------------------------------------------------------------------------
// Net_3152505995976: point-cloud classifier forward pass on MI355X.
// Round 12: dd2 occupancy/latency fix (59us -> target ~35us).
//   - dd2: 512 threads / 8 waves per block; each wave owns ONE 16-col
//     group (breg 24 VGPR, acc 20 VGPR) -> deep gather pipelining + 2x
//     waves; X-build 5 iters/thread. MFMA order/epilogue unchanged ->
//     bit-identical output.
//   - everything else identical to the passing R11 kernel.
// ---------------------------------------------------------------------------

#define NEW_SLARTG 1

typedef unsigned short u16;
typedef unsigned int u32;
typedef unsigned long long u64;
typedef __attribute__((ext_vector_type(8))) short short8;
typedef __attribute__((ext_vector_type(4))) float f32x4;

#define BB 8
#define NNp 2048
#define KKn 20
#define NP 16384      // BB*NNp
#define EE 327680     // NP*KKn

// ---------------- small helpers ----------------
__device__ __forceinline__ u32 fkey(float f) {
  u32 u = __float_as_uint(f);
  return (u & 0x80000000u) ? ~u : (u | 0x80000000u);
}
__device__ __forceinline__ float funkey(u32 k) {
  u32 u = (k & 0x80000000u) ? (k ^ 0x80000000u) : ~k;
  return __uint_as_float(u);
}
__device__ __forceinline__ float f_sign(float a, float b) {
  return (b >= 0.f) ? fabsf(a) : -fabsf(a);
}
__device__ __forceinline__ u16 f2bf(float f) {
  u32 u = __float_as_uint(f);
  u32 r = (u + 0x7fffu + ((u >> 16) & 1u)) >> 16;
  return (u16)r;
}

__device__ __forceinline__ u64 sxor64(u64 v, int m) {
  union { u64 q; u32 d[2]; } a; a.q = v;
  a.d[0] = __shfl_xor(a.d[0], m);
  a.d[1] = __shfl_xor(a.d[1], m);
  return a.q;
}
__device__ __forceinline__ u64 sidx64(u64 v, int src) {
  union { u64 q; u32 d[2]; } a; a.q = v;
  a.d[0] = __shfl(a.d[0], src);
  a.d[1] = __shfl(a.d[1], src);
  return a.q;
}
// wave-wide bitonic sort, 64 u64 elements (1/lane), ascending
__device__ __forceinline__ void bsort64(u64& v, int lane) {
#pragma unroll
  for (int k = 2; k <= 64; k <<= 1) {
#pragma unroll
    for (int j = k >> 1; j > 0; j >>= 1) {
      u64 pv = sxor64(v, j);
      bool up = ((lane & k) == 0);
      bool lower = ((lane & j) == 0);
      bool keepmin = (lower == up);
      bool take = keepmin ? (pv < v) : (pv > v);
      v = take ? pv : v;
    }
  }
}

// ---------------- LAPACK fp32 replicas ----------------
__device__ float slapy2_(float x, float y) {
#pragma clang fp contract(off)
  float xa = fabsf(x), ya = fabsf(y);
  float w = fmaxf(xa, ya), z = fminf(xa, ya);
  if (z == 0.f) return w;
  float t = z / w;
  return w * sqrtf(1.0f + t * t);
}

__device__ void slartg_(float f, float g, float& c, float& s, float& r) {
#pragma clang fp contract(off)
#if NEW_SLARTG
  const float safmin = 1.17549435e-38f;
  const float safmax = 8.50705917e+37f;
  const float rtmin = 1.08420217e-19f;   // sqrt(safmin)
  const float rtmax = 6.52221171e+18f;   // sqrt(safmax/2)
  float f1 = fabsf(f), g1 = fabsf(g);
  if (g == 0.f) { c = 1.f; s = 0.f; r = f; }
  else if (f == 0.f) { c = 0.f; s = (g >= 0.f) ? 1.f : -1.f; r = g1; }
  else {
    float d;
    if (f1 > rtmin && f1 < rtmax && g1 > rtmin && g1 < rtmax) {
      d = sqrtf(f * f + g * g);
      c = f1 / d;
      r = (f >= 0.f) ? d : -d;
    } else {
      float uu = fminf(safmax, fmaxf(safmin, fmaxf(f1, g1)));
      float fs = f / uu, gs = g / uu;
      d = sqrtf(fs * fs + gs * gs);
      c = fabsf(fs) / d;
      r = ((f >= 0.f) ? d : -d) * uu;
    }
    s = g / r;
  }
#else
  if (g == 0.f) { c = 1.f; s = 0.f; r = f; }
  else if (f == 0.f) { c = 0.f; s = 1.f; r = g; }
  else {
    float f1 = f, g1 = g;
    r = sqrtf(f1 * f1 + g1 * g1);
    c = f1 / r;
    s = g1 / r;
    if (fabsf(f) > fabsf(g) && c < 0.f) { c = -c; s = -s; r = -r; }
  }
#endif
}

__device__ void slaev2_(float a, float b, float c, float& rt1, float& rt2,
                        float& cs1, float& sn1) {
#pragma clang fp contract(off)
  float sm = a + c;
  float df = a - c;
  float adf = fabsf(df);
  float tb = b + b;
  float ab = fabsf(tb);
  float acmx, acmn;
  if (fabsf(a) > fabsf(c)) { acmx = a; acmn = c; } else { acmx = c; acmn = a; }
  float rt;
  if (adf > ab) { float t = ab / adf; rt = adf * sqrtf(1.f + t * t); }
  else if (adf < ab) { float t = adf / ab; rt = ab * sqrtf(1.f + t * t); }
  else { rt = ab * sqrtf(2.f); }
  int sgn1;
  if (sm < 0.f) {
    rt1 = 0.5f * (sm - rt); sgn1 = -1;
    rt2 = (acmx / rt1) * acmn - (b / rt1) * b;
  } else if (sm > 0.f) {
    rt1 = 0.5f * (sm + rt); sgn1 = 1;
    rt2 = (acmx / rt1) * acmn - (b / rt1) * b;
  } else {
    rt1 = 0.5f * rt; rt2 = -0.5f * rt; sgn1 = 1;
  }
  float cs; int sgn2;
  if (df >= 0.f) { cs = df + rt; sgn2 = 1; } else { cs = df - rt; sgn2 = -1; }
  float acs = fabsf(cs);
  if (acs > ab) {
    float ct = -tb / cs;
    sn1 = 1.f / sqrtf(1.f + ct * ct);
    cs1 = ct * sn1;
  } else {
    if (ab == 0.f) { cs1 = 1.f; sn1 = 0.f; }
    else {
      float tn = -cs / tb;
      cs1 = 1.f / sqrtf(1.f + tn * tn);
      sn1 = tn * cs1;
    }
  }
  if (sgn1 == sgn2) { float tn = cs1; cs1 = -sn1; sn1 = tn; }
}

// ssteqr for n=3, compz='I' (z must be identity on entry)
__device__ void ssteqr3_(float* d, float* e, float z[3][3]) {
#pragma clang fp contract(off)
  const float eps = 5.9604645e-08f;
  const float eps2 = 3.5527137e-15f;
  const float safmin = 1.17549435e-38f;
  const int n = 3;
  const int nmaxit = 90;
  int jtot = 0;
  int l1 = 1;

  while (1) {
    if (l1 > n) break;
    if (l1 > 1) e[l1 - 2] = 0.f;
    int m = n;
    if (l1 <= n - 1) {
      for (int mm = l1; mm <= n - 1; ++mm) {
        float tst = fabsf(e[mm - 1]);
        if (tst == 0.f) { m = mm; break; }
        if (tst <= (sqrtf(fabsf(d[mm - 1])) * sqrtf(fabsf(d[mm]))) * eps) {
          e[mm - 1] = 0.f; m = mm; break;
        }
      }
    }
    int l = l1, lsv = l, lend = m, lendsv = lend;
    (void)lsv; (void)lendsv;
    l1 = m + 1;
    if (lend == l) continue;

    float anorm = 0.f;
    for (int i = l; i <= lend; ++i) anorm = fmaxf(anorm, fabsf(d[i - 1]));
    for (int i = l; i <= lend - 1; ++i) anorm = fmaxf(anorm, fabsf(e[i - 1]));
    if (anorm == 0.f) continue;

    if (fabsf(d[lend - 1]) < fabsf(d[l - 1])) { lend = lsv; l = lendsv; }

    if (lend > l) {
      // --- QL iteration ---
      while (1) {
        int m2 = lend;
        if (l != lend) {
          for (int mm = l; mm <= lend - 1; ++mm) {
            float tst = fabsf(e[mm - 1]); tst = tst * tst;
            if (tst <= (eps2 * fabsf(d[mm - 1])) * fabsf(d[mm]) + safmin) { m2 = mm; break; }
          }
        }
        if (m2 < lend) e[m2 - 1] = 0.f;
        float p = d[l - 1];
        if (m2 == l) {
          d[l - 1] = p; l += 1;
          if (l <= lend) continue;
          break;
        }
        if (m2 == l + 1) {
          float rt1, rt2, cc, ss;
          slaev2_(d[l - 1], e[l - 1], d[l], rt1, rt2, cc, ss);
          for (int i = 0; i < 3; ++i) {
            float temp = z[i][l];
            z[i][l] = cc * temp - ss * z[i][l - 1];
            z[i][l - 1] = ss * temp + cc * z[i][l - 1];
          }
          d[l - 1] = rt1; d[l] = rt2; e[l - 1] = 0.f;
          l += 2;
          if (l <= lend) continue;
          break;
        }
        if (jtot == nmaxit) break;
        jtot++;
        float g = (d[l] - p) / (2.f * e[l - 1]);
        float r = slapy2_(g, 1.f);
        g = d[m2 - 1] - p + (e[l - 1] / (g + f_sign(r, g)));
        float s = 1.f, c = 1.f;
        p = 0.f;
        float csv[2], snv[2];
        for (int i = m2 - 1; i >= l; --i) {
          float f = s * e[i - 1];
          float b = c * e[i - 1];
          slartg_(g, f, c, s, r);
          if (i != m2 - 1) e[i] = r;
          g = d[i] - p;
          r = (d[i - 1] - g) * s + (2.f * c) * b;
          p = s * r;
          d[i] = g + p;
          g = c * r - b;
          csv[i - l] = c; snv[i - l] = -s;
        }
        int cnt = m2 - l;
        for (int j = cnt; j >= 1; --j) {       // slasr 'R','V','B'
          float cj = csv[j - 1], sj = snv[j - 1];
          int c0 = (l - 1) + (j - 1);
          for (int i = 0; i < 3; ++i) {
            float temp = z[i][c0 + 1];
            z[i][c0 + 1] = cj * temp - sj * z[i][c0];
            z[i][c0] = sj * temp + cj * z[i][c0];
          }
        }
        d[l - 1] = d[l - 1] - p;
        e[l - 1] = g;
      }
    } else {
      // --- QR iteration ---
      while (1) {
        int m2 = lend;
        if (l != lend) {
          for (int mm = l; mm >= lend + 1; --mm) {
            float tst = fabsf(e[mm - 2]); tst = tst * tst;
            if (tst <= (eps2 * fabsf(d[mm - 1])) * fabsf(d[mm - 2]) + safmin) { m2 = mm; break; }
          }
        }
        if (m2 > lend) e[m2 - 2] = 0.f;
        float p = d[l - 1];
        if (m2 == l) {
          d[l - 1] = p; l -= 1;
          if (l >= lend) continue;
          break;
        }
        if (m2 == l - 1) {
          float rt1, rt2, cc, ss;
          slaev2_(d[l - 2], e[l - 2], d[l - 1], rt1, rt2, cc, ss);
          for (int i = 0; i < 3; ++i) {
            float temp = z[i][l - 1];
            z[i][l - 1] = cc * temp - ss * z[i][l - 2];
            z[i][l - 2] = ss * temp + cc * z[i][l - 2];
          }
          d[l - 2] = rt1; d[l - 1] = rt2; e[l - 2] = 0.f;
          l -= 2;
          if (l >= lend) continue;
          break;
        }
        if (jtot == nmaxit) break;
        jtot++;
        float g = (d[l - 2] - p) / (2.f * e[l - 2]);
        float r = slapy2_(g, 1.f);
        g = d[m2 - 1] - p + (e[l - 2] / (g + f_sign(r, g)));
        float s = 1.f, c = 1.f;
        p = 0.f;
        float csv[2], snv[2];
        for (int i = m2; i <= l - 1; ++i) {
          float f = s * e[i - 1];
          float b = c * e[i - 1];
          slartg_(g, f, c, s, r);
          if (i != m2) e[i - 2] = r;
          g = d[i - 1] - p;
          r = (d[i] - g) * s + (2.f * c) * b;
          p = s * r;
          d[i - 1] = g + p;
          g = c * r - b;
          csv[i - m2] = c; snv[i - m2] = s;
        }
        int cnt = l - m2;
        for (int j = 1; j <= cnt; ++j) {       // slasr 'R','V','F'
          float cj = csv[j - 1], sj = snv[j - 1];
          int c0 = (m2 - 1) + (j - 1);
          for (int i = 0; i < 3; ++i) {
            float temp = z[i][c0 + 1];
            z[i][c0 + 1] = cj * temp - sj * z[i][c0];
            z[i][c0] = sj * temp + cj * z[i][c0];
          }
        }
        d[l - 1] = d[l - 1] - p;
        e[l - 2] = g;
      }
    }
  }

  // selection sort ascending, swap eigenvector columns (LAPACK exact)
  for (int ii = 2; ii <= n; ++ii) {
    int i = ii - 1, k = i;
    float p = d[i - 1];
    for (int j = ii; j <= n; ++j)
      if (d[j - 1] < p) { k = j; p = d[j - 1]; }
    if (k != i) {
      d[k - 1] = d[i - 1]; d[i - 1] = p;
      for (int r2 = 0; r2 < 3; ++r2) {
        float t = z[r2][i - 1]; z[r2][i - 1] = z[r2][k - 1]; z[r2][k - 1] = t;
      }
    }
  }
}

// full ssyevd replica for 3x3 symmetric (lower entries), eigenvectors only
__device__ void eigh3_(float a00, float a10, float a11, float a20, float a21,
                       float a22, float V[3][3]) {
#pragma clang fp contract(off)
  float d0, d1, d2, e0, e1, tau1 = 0.f, v2 = 0.f;
  {
    float alpha = a10;
    float xnorm = fabsf(a20);
    if (xnorm == 0.f) {
      tau1 = 0.f; v2 = 0.f;
      e0 = alpha; d0 = a00; d1 = a11; d2 = a22; e1 = a21;
    } else {
      float beta = -f_sign(slapy2_(alpha, xnorm), alpha);
      tau1 = (beta - alpha) / beta;
      float inv = 1.0f / (alpha - beta);
      v2 = a20 * inv;
      float y0 = tau1 * a11;
      float y1v = tau1 * a21;
      float temp2 = a21 * v2;
      y0 = y0 + tau1 * temp2;
      y1v = y1v + (tau1 * v2) * a22;
      float dotyv = y0 * 1.f + y1v * v2;
      float al = (-0.5f * tau1) * dotyv;
      float w0 = y0 + al * 1.f;
      float w1 = y1v + al * v2;
      a11 = (a11 + 1.f * (-w0)) + w0 * (-1.f);
      a21 = (a21 + v2 * (-w0)) + w1 * (-1.f);
      a22 = (a22 + v2 * (-w1)) + w1 * (-v2);
      e0 = beta; d0 = a00; d1 = a11; d2 = a22; e1 = a21;
    }
  }
  float dd[3] = { d0, d1, d2 };
  float ee[2] = { e0, e1 };
  float z[3][3] = { {1.f,0.f,0.f},{0.f,1.f,0.f},{0.f,0.f,1.f} };
  ssteqr3_(dd, ee, z);
  if (tau1 != 0.f) {
    for (int j = 0; j < 3; ++j) {
      float wj = z[1][j] * 1.f + z[2][j] * v2;
      float temp = -tau1 * wj;
      z[1][j] = z[1][j] + 1.f * temp;
      z[2][j] = z[2][j] + v2 * temp;
    }
  }
  for (int r = 0; r < 3; ++r)
    for (int cix = 0; cix < 3; ++cix)
      V[r][cix] = z[r][cix];
}

// ---------------- kernels ----------------

// init: zero BN1-3 buckets + y1key, split W12/W13 to bf16 hi/lo
__global__ __launch_bounds__(256) void init_kernel(double* __restrict__ sb,
                                                   u32* __restrict__ y1k,
                                                   const float* __restrict__ w12,
                                                   const float* __restrict__ w13,
                                                   u16* __restrict__ wsp) {
  int id = blockIdx.x * 256 + threadIdx.x;
  if (id < 24576) sb[id] = 0.0;
  if (id < 8192) {
    y1k[id] = 0u;
    int layer = id >> 12;
    int nk = id & 4095;
    int n = nk >> 6, k = nk & 63;
    const float* W = layer ? w13 : w12;
    float v = W[(size_t)k * 64 + n];
    u16 hi = f2bf(v);
    float rem = v - __uint_as_float(((u32)hi) << 16);
    u16 lo = f2bf(rem);
    wsp[layer * 8192 + n * 64 + k] = hi;
    wsp[layer * 8192 + 4096 + n * 64 + k] = lo;
  }
}

// exact KNN top-20 per point: threshold-select + wave bitonic sort.
__global__ __launch_bounds__(256) void knn_kernel(const float* __restrict__ pos,
                                                  int* __restrict__ idx) {
#pragma clang fp contract(off)
  __shared__ u64 cke[4][128];
  int w = threadIdx.x >> 6;
  int lane = threadIdx.x & 63;
  int wid = blockIdx.x * 4 + w;
  int b = wid >> 11;
  int n = wid & 2047;
  const float* pc = pos + (size_t)b * NNp * 3;
  float qx = pc[n * 3 + 0], qy = pc[n * 3 + 1], qz = pc[n * 3 + 2];
  float d2n = (qx * qx + qy * qy) + qz * qz;

  u32 kreg[32];
  u32 mk = 0xFFFFFFFFu;
#pragma unroll
  for (int t = 0; t < 32; ++t) {
    int m = lane + 64 * t;
    float x = pc[m * 3 + 0], y = pc[m * 3 + 1], zc = pc[m * 3 + 2];
    float d2m = (x * x + y * y) + zc * zc;
    float dot = (qx * x + qy * y) + qz * zc;
    float dist = (d2n + d2m) - 2.0f * dot;
    u32 key = fkey(dist);
    if (m == n) key = 0xFFFFFFFFu;
    kreg[t] = key;
    mk = key < mk ? key : mk;
  }
#pragma unroll
  for (int off = 32; off; off >>= 1) {
    u32 o = __shfl_xor(mk, off);
    mk = o < mk ? o : mk;
  }

  u32 lo_b = mk - 1u, hi_b = 0xFFFFFFFEu;
  int c_hi = 2047;
  float tf = funkey(mk) * 7.368f;
  u32 T = fkey(tf);
  if (T < mk) T = mk;
  if (T > 0xFFFFFFFEu) T = 0xFFFFFFFEu;
  for (int it = 0; it < 48; ++it) {
    int cnt = 0;
#pragma unroll
    for (int t = 0; t < 32; ++t) cnt += (kreg[t] <= T) ? 1 : 0;
#pragma unroll
    for (int off = 32; off; off >>= 1) cnt += __shfl_xor(cnt, off);
    if (cnt >= 20) {
      hi_b = T; c_hi = cnt;
      if (cnt <= 128) break;
    } else {
      lo_b = T;
    }
    if (hi_b <= lo_b + 1u) break;
    u32 Tn;
    if (it < 12) {
      float tfc = funkey(T);
      int cc = cnt < 1 ? 1 : cnt;
      float guess = tfc * __builtin_exp2f(0.66667f * __builtin_log2f(45.0f / (float)cc));
      Tn = fkey(guess);
      if (!(Tn > lo_b && Tn < hi_b)) Tn = lo_b + ((hi_b - lo_b) >> 1);
    } else {
      Tn = lo_b + ((hi_b - lo_b) >> 1);
    }
    T = Tn;
  }

  u64* ck = cke[w];
  u32 base = 0;
#pragma unroll
  for (int t = 0; t < 32; ++t) {
    bool pass = kreg[t] <= hi_b;
    u64 ball = __ballot(pass);
    if (pass) {
      u32 posn = base + (u32)__popcll(ball & ((1ull << lane) - 1ull));
      if (posn < 128u)
        ck[posn] = ((u64)kreg[t] << 32) | (u32)(lane + 64 * t);
    }
    base += (u32)__popcll(ball);
  }
  if (base > 128u) {
    base = 0;
#pragma unroll
    for (int t = 0; t < 32; ++t) {
      bool pass = kreg[t] <= lo_b;
      u64 ball = __ballot(pass);
      if (pass) {
        u32 posn = base + (u32)__popcll(ball & ((1ull << lane) - 1ull));
        ck[posn] = ((u64)kreg[t] << 32) | (u32)(lane + 64 * t);
      }
      base += (u32)__popcll(ball);
    }
#pragma unroll
    for (int t = 0; t < 32; ++t) {
      bool pass = (kreg[t] > lo_b) && (kreg[t] <= hi_b);
      u64 ball = __ballot(pass);
      if (pass) {
        u32 posn = base + (u32)__popcll(ball & ((1ull << lane) - 1ull));
        if (posn < 128u)
          ck[posn] = ((u64)kreg[t] << 32) | (u32)(lane + 64 * t);
      }
      base += (u32)__popcll(ball);
    }
  }
  u32 ctot = base < 128u ? base : 128u;

  u64 e0 = (lane < (int)ctot) ? ck[lane] : ~0ull;
  bsort64(e0, lane);
  if (ctot > 64u) {
    u64 e1 = (lane + 64 < (int)ctot) ? ck[lane + 64] : ~0ull;
    bsort64(e1, lane);
    u64 r = sidx64(e1, 63 - lane);
    u64 mn = r < e0 ? r : e0;
#pragma unroll
    for (int j = 32; j > 0; j >>= 1) {
      u64 pv = sxor64(mn, j);
      bool lower2 = ((lane & j) == 0);
      bool take = lower2 ? (pv < mn) : (pv > mn);
      mn = take ? pv : mn;
    }
    e0 = mn;
  }
  if (lane < 20)
    idx[(size_t)wid * 20 + lane] = (int)(u32)(e0 & 0xFFFFFFFFull);
}

// per-point: covariance, LAPACK-replica eigh, loc = rel @ V
__global__ __launch_bounds__(64) void prep_kernel(const float* __restrict__ pos,
                                                  const int* __restrict__ idx,
                                                  float* __restrict__ loc,
                                                  float* __restrict__ Vout) {
#pragma clang fp contract(off)
  int p = blockIdx.x * 64 + threadIdx.x;
  int b = p >> 11, n = p & 2047;
  const float* pc = pos + (size_t)b * NNp * 3;
  float qx = pc[n * 3 + 0], qy = pc[n * 3 + 1], qz = pc[n * 3 + 2];
  const int* ip = idx + (size_t)p * 20;
  float c00 = 0, c01 = 0, c02 = 0, c11 = 0, c12 = 0, c22 = 0;
  for (int k = 0; k < 20; ++k) {
    int j = ip[k];
    float rx = pc[j * 3 + 0] - qx, ry = pc[j * 3 + 1] - qy, rz = pc[j * 3 + 2] - qz;
    c00 += rx * rx; c01 += rx * ry; c02 += rx * rz;
    c11 += ry * ry; c12 += ry * rz; c22 += rz * rz;
  }
  float Vm[3][3];
  eigh3_(c00, c01, c11, c02, c12, c22, Vm);
  float* vp = Vout + (size_t)p * 9;
  for (int d = 0; d < 3; ++d)
    for (int e = 0; e < 3; ++e) vp[d * 3 + e] = Vm[d][e];
  for (int k = 0; k < 20; ++k) {
    int j = ip[k];
    float rx = pc[j * 3 + 0] - qx, ry = pc[j * 3 + 1] - qy, rz = pc[j * 3 + 2] - qz;
    float l0 = rx * Vm[0][0] + ry * Vm[1][0] + rz * Vm[2][0];
    float l1 = rx * Vm[0][1] + ry * Vm[1][1] + rz * Vm[2][1];
    float l2 = rx * Vm[0][2] + ry * Vm[1][2] + rz * Vm[2][2];
    size_t e = ((size_t)p * 20 + k) * 3;
    loc[e + 0] = l0; loc[e + 1] = l1; loc[e + 2] = l2;
  }
}

// layer1: [E,3]@[3,64]+b, relu, store fp32; fused per-channel stats
__global__ __launch_bounds__(256) void l1_kernel(const float* __restrict__ loc,
                                                 const float* __restrict__ W,
                                                 const float* __restrict__ bias,
                                                 float* __restrict__ h1,
                                                 double* __restrict__ sb) {
  __shared__ float sW[192];
  __shared__ float sB[64];
  __shared__ float red[512];
  int t = threadIdx.x;
  if (t < 192) sW[t] = W[t];
  if (t < 64) sB[t] = bias[t];
  __syncthreads();
  int w = t >> 6, c = t & 63;
  size_t e0 = (size_t)blockIdx.x * 256 + w * 64;
  float wc0 = sW[c], wc1 = sW[64 + c], wc2 = sW[128 + c], bc = sB[c];
  float s = 0.f, q = 0.f;
  for (int e = 0; e < 64; ++e) {
    float x0 = loc[(e0 + e) * 3 + 0];
    float x1 = loc[(e0 + e) * 3 + 1];
    float x2 = loc[(e0 + e) * 3 + 2];
    float z = fmaxf(bc + x0 * wc0 + x1 * wc1 + x2 * wc2, 0.f);
    h1[(e0 + e) * 64 + c] = z;
    s += z; q += z * z;
  }
  red[w * 64 + c] = s;
  red[256 + w * 64 + c] = q;
  __syncthreads();
  if (t < 64) {
    float S = red[t] + red[64 + t] + red[128 + t] + red[192 + t];
    float Q = red[256 + t] + red[320 + t] + red[384 + t] + red[448 + t];
    atomicAdd(&sb[((int)blockIdx.x & 63) * 128 + t], (double)S);
    atomicAdd(&sb[((int)blockIdx.x & 63) * 128 + 64 + t], (double)Q);
  }
}

// 64-bucket stats (64 ch) -> per-channel BN affine (fixed-order reduce)
__global__ void finalizeB_kernel(const double* __restrict__ sb,
                                 const float* __restrict__ g,
                                 const float* __restrict__ be,
                                 float* __restrict__ outp) {
  int c = threadIdx.x;
  if (c >= 64) return;
  double s = 0.0, q = 0.0;
  for (int buk = 0; buk < 64; ++buk) {
    s += sb[buk * 128 + c];
    q += sb[buk * 128 + 64 + c];
  }
  double m = s / (double)EE;
  double var = q / (double)EE - m * m;
  double inv = 1.0 / sqrt(var + 1e-5);
  double sc = (double)g[c] * inv;
  outp[c] = (float)sc;
  outp[64 + c] = (float)((double)be[c] - m * sc);
}

// 64-bucket stats (128 ch) -> BN4 affine (fixed-order bucket reduce)
__global__ void finalize64_kernel(const double* __restrict__ s4b,
                                  const float* __restrict__ g,
                                  const float* __restrict__ be,
                                  float* __restrict__ outp) {
  int c = threadIdx.x;
  double s = 0.0, q = 0.0;
  for (int buk = 0; buk < 64; ++buk) {
    s += s4b[buk * 256 + c];
    q += s4b[buk * 256 + 128 + c];
  }
  double m = s / (double)EE;
  double var = q / (double)EE - m * m;
  double inv = 1.0 / sqrt(var + 1e-5);
  double sc = (double)g[c] * inv;
  outp[c] = (float)sc;
  outp[128 + c] = (float)((double)be[c] - m * sc);
}

// layers 2/3 via split-bf16 MFMA (fp32-grade accuracy); fused stats
__global__ __launch_bounds__(256) void l23_kernel(const float* __restrict__ hin,
                                                  const float* __restrict__ ss,
                                                  const u16* __restrict__ whi,
                                                  const u16* __restrict__ wlo,
                                                  const float* __restrict__ bias,
                                                  float* __restrict__ hout,
                                                  double* __restrict__ sb) {
  __shared__ u16 sHI[128 * 72];
  __shared__ u16 sLO[128 * 72];
  int t = threadIdx.x;
  size_t e0 = (size_t)blockIdx.x * 128;
  int w = t >> 6, l = t & 63;
  int lr = l & 15, lg = l >> 4;

  short8 bhi[4][2], blo[4][2];
#pragma unroll
  for (int nt = 0; nt < 4; ++nt)
#pragma unroll
    for (int ks = 0; ks < 2; ++ks) {
      int off = (nt * 16 + lr) * 64 + ks * 32 + lg * 8;
      bhi[nt][ks] = *(const short8*)&whi[off];
      blo[nt][ks] = *(const short8*)&wlo[off];
    }

  for (int v = t; v < 128 * 16; v += 256) {
    int el = v >> 4, cq = v & 15;
    float4 x4 = *(const float4*)&hin[(e0 + el) * 64 + cq * 4];
    float4 sc4 = *(const float4*)&ss[cq * 4];
    float4 sh4 = *(const float4*)&ss[64 + cq * 4];
    float vv[4];
    vv[0] = x4.x * sc4.x + sh4.x;
    vv[1] = x4.y * sc4.y + sh4.y;
    vv[2] = x4.z * sc4.z + sh4.z;
    vv[3] = x4.w * sc4.w + sh4.w;
    u16 hi[4], lo[4];
#pragma unroll
    for (int j = 0; j < 4; ++j) {
      hi[j] = f2bf(vv[j]);
      float rem = vv[j] - __uint_as_float(((u32)hi[j]) << 16);
      lo[j] = f2bf(rem);
    }
    u32* ph = (u32*)&sHI[el * 72 + cq * 4];
    ph[0] = (u32)hi[0] | ((u32)hi[1] << 16);
    ph[1] = (u32)hi[2] | ((u32)hi[3] << 16);
    u32* pl = (u32*)&sLO[el * 72 + cq * 4];
    pl[0] = (u32)lo[0] | ((u32)lo[1] << 16);
    pl[1] = (u32)lo[2] | ((u32)lo[3] << 16);
  }
  __syncthreads();

  f32x4 acc[2][4];
#pragma unroll
  for (int mt = 0; mt < 2; ++mt)
#pragma unroll
    for (int nt = 0; nt < 4; ++nt) acc[mt][nt] = (f32x4)(0.f);

#pragma unroll
  for (int ks = 0; ks < 2; ++ks) {
    const int kb = ks * 32 + lg * 8;
#pragma unroll
    for (int mt = 0; mt < 2; ++mt) {
      int row = w * 32 + mt * 16 + lr;
      short8 ah = *(const short8*)&sHI[row * 72 + kb];
      short8 al = *(const short8*)&sLO[row * 72 + kb];
#pragma unroll
      for (int nt = 0; nt < 4; ++nt) {
        acc[mt][nt] = __builtin_amdgcn_mfma_f32_16x16x32_bf16(ah, bhi[nt][ks], acc[mt][nt], 0, 0, 0);
        acc[mt][nt] = __builtin_amdgcn_mfma_f32_16x16x32_bf16(al, bhi[nt][ks], acc[mt][nt], 0, 0, 0);
        acc[mt][nt] = __builtin_amdgcn_mfma_f32_16x16x32_bf16(ah, blo[nt][ks], acc[mt][nt], 0, 0, 0);
      }
    }
  }

#pragma unroll
  for (int nt = 0; nt < 4; ++nt) {
    int o = nt * 16 + lr;
    float bs = bias[o];
    float s = 0.f, q = 0.f;
#pragma unroll
    for (int mt = 0; mt < 2; ++mt) {
#pragma unroll
      for (int r = 0; r < 4; ++r) {
        float z = fmaxf(acc[mt][nt][r] + bs, 0.f);
        size_t e = e0 + w * 32 + mt * 16 + lg * 4 + r;
        hout[e * 64 + o] = z;
        s += z; q += z * z;
      }
    }
    s += __shfl_xor(s, 16); s += __shfl_xor(s, 32);
    q += __shfl_xor(q, 16); q += __shfl_xor(q, 32);
    if (l < 16) {
      atomicAdd(&sb[((int)blockIdx.x & 63) * 128 + o], (double)s);
      atomicAdd(&sb[((int)blockIdx.x & 63) * 128 + 64 + o], (double)q);
    }
  }
}

// f3d[p][c][d] = max_k h3n[p,k,c] * loc[p,k,d]
__global__ __launch_bounds__(256) void f3d_kernel(const float* __restrict__ h3,
                                                  const float* __restrict__ ss3,
                                                  const float* __restrict__ loc,
                                                  float* __restrict__ f3d) {
  int t = threadIdx.x;
  int p = blockIdx.x * 4 + (t >> 6);
  int c = t & 63;
  float sc = ss3[c], sh = ss3[64 + c];
  float m0 = -__builtin_inff(), m1 = m0, m2 = m0;
  size_t eb = (size_t)p * 20;
  for (int k = 0; k < 20; ++k) {
    size_t e = eb + k;
    float h = h3[e * 64 + c] * sc + sh;
    float l0 = loc[e * 3 + 0], l1 = loc[e * 3 + 1], l2 = loc[e * 3 + 2];
    m0 = fmaxf(m0, h * l0);
    m1 = fmaxf(m1, h * l1);
    m2 = fmaxf(m2, h * l2);
  }
  size_t o = (size_t)p * 192 + c * 3;
  f3d[o + 0] = m0; f3d[o + 1] = m1; f3d[o + 2] = m2;
}

// W21 [192][128] fp32 -> WT bf16 [128][192]; also zeroes the s4b buckets
__global__ __launch_bounds__(256) void wtcvt_kernel(const float* __restrict__ W,
                                                    u16* __restrict__ wt,
                                                    double* __restrict__ s4b) {
  int id = blockIdx.x * 256 + threadIdx.x;
  if (id < 192 * 128) {
    int n = id / 192, k = id - n * 192;
    wt[id] = f2bf(W[(size_t)k * 128 + n]);
  }
  if (id < 64 * 256) s4b[id] = 0.0;
}

// DD2 via bf16 MFMA: 512 threads / 8 waves; each wave owns one 16-col
// group (low VGPR -> deep gather pipelining). cloud->XCD swizzle; X bf16
// LDS [80][200]; quad-aligned maxpool; bucketed stats; fdd2T output.
// MFMA order per accumulator identical to R11 -> bit-identical results.
__global__ __launch_bounds__(512) void dd2_kernel(const float* __restrict__ f3d,
                                                  const float* __restrict__ Vmat,
                                                  const int* __restrict__ idx,
                                                  const u16* __restrict__ wt,
                                                  const float* __restrict__ bias,
                                                  float* __restrict__ fdd2T,
                                                  double* __restrict__ s4b) {
  __shared__ u16 sX[80 * 200];
  __shared__ float sV[36];
  __shared__ int sJ[80];
  int t = threadIdx.x;
  int wk = (blockIdx.x & 7) * 512 + (blockIdx.x >> 3);
  int p0 = wk * 4;
  int bcl = p0 >> 11;
  int buk = ((int)blockIdx.x & 63) << 8;

  int w = t >> 6, l = t & 63;
  int lr = l & 15, lg = l >> 4;
  int col = w * 16 + lr;            // this wave's column group

  // preload B fragments for this wave's single column group
  short8 breg[6];
#pragma unroll
  for (int s = 0; s < 6; ++s) {
    const int kk = (s / 3) * 96 + (s % 3) * 32 + lg * 8;
    breg[s] = *(const short8*)&wt[col * 192 + kk];
  }

  if (t < 36) sV[t] = Vmat[(size_t)p0 * 9 + t];
  if (t < 80) sJ[t] = ((bcl << 11) + idx[(size_t)p0 * 20 + t]) * 192;
  __syncthreads();

  // build X: 5 iterations per thread (2560 slots / 512 threads)
  for (int v = t; v < 80 * 32; v += 512) {
    int el = v >> 5, c2 = v & 31;
    int pp = el / 20;
    const float* fp = f3d + (size_t)sJ[el] + 6 * c2;
    float2 f01 = *(const float2*)(fp);
    float2 f23 = *(const float2*)(fp + 2);
    float2 f45 = *(const float2*)(fp + 4);
    float f0 = f01.x, f1 = f01.y, f2 = f23.x;
    float f3 = f23.y, f4 = f45.x, f5 = f45.y;
    const float* Vp = &sV[pp * 9];
    float x0 = f0 * Vp[0] + f1 * Vp[3] + f2 * Vp[6];
    float x1 = f0 * Vp[1] + f1 * Vp[4] + f2 * Vp[7];
    float x2 = f0 * Vp[2] + f1 * Vp[5] + f2 * Vp[8];
    float y0 = f3 * Vp[0] + f4 * Vp[3] + f5 * Vp[6];
    float y1 = f3 * Vp[1] + f4 * Vp[4] + f5 * Vp[7];
    float y2 = f3 * Vp[2] + f4 * Vp[5] + f5 * Vp[8];
    u32* xp = (u32*)&sX[el * 200 + 6 * c2];
    xp[0] = (u32)f2bf(x0) | ((u32)f2bf(x1) << 16);
    xp[1] = (u32)f2bf(x2) | ((u32)f2bf(y0) << 16);
    xp[2] = (u32)f2bf(y1) | ((u32)f2bf(y2) << 16);
  }
  __syncthreads();

  f32x4 acc[5];
#pragma unroll
  for (int mt = 0; mt < 5; ++mt) acc[mt] = (f32x4)(0.f);

  // K-steps: per-acc order identical to R11 (s = 0..5 ascending)
#pragma unroll
  for (int s = 0; s < 6; ++s) {
    const int kbase = (s / 3) * 96 + (s % 3) * 32 + lg * 8;
#pragma unroll
    for (int mt = 0; mt < 5; ++mt) {
      short8 a = *(const short8*)&sX[(mt * 16 + lr) * 200 + kbase];
      acc[mt] = __builtin_amdgcn_mfma_f32_16x16x32_bf16(a, breg[s], acc[mt], 0, 0, 0);
    }
  }

  // epilogue: quad-aligned maxpool; per-channel stats; transposed store
  {
    float bs = bias[col];
    float pm0 = 0.f, pm1 = 0.f, pm2 = 0.f, pm3 = 0.f;
    float s = 0.f, q = 0.f;
#pragma unroll
    for (int mt = 0; mt < 5; ++mt) {
      int qs = mt * 16 + lg * 4;     // quad start edge (multiple of 4)
      int qp = qs / 20;              // owning point 0..3
      float z0 = fmaxf(acc[mt][0] + bs, 0.f);
      float z1 = fmaxf(acc[mt][1] + bs, 0.f);
      float z2 = fmaxf(acc[mt][2] + bs, 0.f);
      float z3 = fmaxf(acc[mt][3] + bs, 0.f);
      s += z0; q += z0 * z0;
      s += z1; q += z1 * z1;
      s += z2; q += z2 * z2;
      s += z3; q += z3 * z3;
      float qm = fmaxf(fmaxf(z0, z1), fmaxf(z2, z3));
      pm0 = fmaxf(pm0, (qp == 0) ? qm : 0.f);
      pm1 = fmaxf(pm1, (qp == 1) ? qm : 0.f);
      pm2 = fmaxf(pm2, (qp == 2) ? qm : 0.f);
      pm3 = fmaxf(pm3, (qp == 3) ? qm : 0.f);
    }
#pragma unroll
    for (int off = 16; off < 64; off <<= 1) {
      pm0 = fmaxf(pm0, __shfl_xor(pm0, off));
      pm1 = fmaxf(pm1, __shfl_xor(pm1, off));
      pm2 = fmaxf(pm2, __shfl_xor(pm2, off));
      pm3 = fmaxf(pm3, __shfl_xor(pm3, off));
      s += __shfl_xor(s, off);
      q += __shfl_xor(q, off);
    }
    if (l < 16) {
      float4 pv;
      pv.x = pm0; pv.y = pm1; pv.z = pm2; pv.w = pm3;
      *(float4*)&fdd2T[(size_t)col * NP + p0] = pv;
      atomicAdd(&s4b[buk + col], (double)s);
      atomicAdd(&s4b[buk + 128 + col], (double)q);
    }
  }
}

// y1: fp32 GEMM [16384,128]@[128,1024] with fused max over n.
// 128Mx128N tile, 8x8 acc/thread; K in FOUR 32-deep LDS stages (32KB).
__global__ __launch_bounds__(256) void y1_kernel(const float* __restrict__ fdd2T,
                                                 const float* __restrict__ ss4,
                                                 const float* __restrict__ wh1,
                                                 u32* __restrict__ y1key) {
  __shared__ float sX[32][128];
  __shared__ float sW[32][128];
  int t = threadIdx.x;
  int mtile = blockIdx.x & 127;
  int ntile = blockIdx.x >> 7;
  int cl = mtile >> 4;
  size_t pbase = (size_t)mtile * 128;
  int c0 = ntile * 128;
  int mg = t >> 4, ng = t & 15;

  float acc[8][8];
#pragma unroll
  for (int i = 0; i < 8; ++i)
#pragma unroll
    for (int j = 0; j < 8; ++j) acc[i][j] = 0.f;

  for (int ks = 0; ks < 4; ++ks) {
    int rr = t >> 5, mq = t & 31;
#pragma unroll
    for (int i = 0; i < 4; ++i) {
      int r = rr + i * 8;
      int k = ks * 32 + r;
      float4 x4 = *(const float4*)&fdd2T[(size_t)k * NP + pbase + mq * 4];
      float sc = ss4[k], sh = ss4[128 + k];
      float4 st;
      st.x = x4.x * sc + sh;
      st.y = x4.y * sc + sh;
      st.z = x4.z * sc + sh;
      st.w = x4.w * sc + sh;
      *(float4*)&sX[r][mq * 4] = st;
      float4 w4 = *(const float4*)&wh1[(size_t)k * 1024 + c0 + mq * 4];
      *(float4*)&sW[r][mq * 4] = w4;
    }
    __syncthreads();
#pragma unroll 8
    for (int kk = 0; kk < 32; ++kk) {
      float4 xa = *(const float4*)&sX[kk][mg * 4];
      float4 xb = *(const float4*)&sX[kk][64 + mg * 4];
      float4 wa = *(const float4*)&sW[kk][ng * 4];
      float4 wb = *(const float4*)&sW[kk][64 + ng * 4];
      float xr[8] = { xa.x, xa.y, xa.z, xa.w, xb.x, xb.y, xb.z, xb.w };
      float wc[8] = { wa.x, wa.y, wa.z, wa.w, wb.x, wb.y, wb.z, wb.w };
#pragma unroll
      for (int i = 0; i < 8; ++i)
#pragma unroll
        for (int j = 0; j < 8; ++j) acc[i][j] += xr[i] * wc[j];
    }
    __syncthreads();
  }

  float colmax[8];
#pragma unroll
  for (int j = 0; j < 8; ++j) {
    float v = acc[0][j];
#pragma unroll
    for (int i = 1; i < 8; ++i) v = fmaxf(v, acc[i][j]);
    colmax[j] = v;
  }
  float* red = &sX[0][0];   // 2048 floats needed; sX has 4096
#pragma unroll
  for (int j = 0; j < 8; ++j) {
    int col = (j < 4) ? (ng * 4 + j) : (64 + ng * 4 + (j - 4));
    red[col * 16 + mg] = colmax[j];
  }
  __syncthreads();
  if (t < 128) {
    float m = red[t * 16];
#pragma unroll
    for (int i = 1; i < 16; ++i) m = fmaxf(m, red[t * 16 + i]);
    atomicMax(&y1key[(size_t)cl * 1024 + c0 + t], fkey(m));
  }
}

// head GEMM layer 1 (1024->512) with FUSED y1 decode+bias+relu+BN staging.
__global__ __launch_bounds__(256) void hgemm1_kernel(const u32* __restrict__ y1k,
                                                     const float* __restrict__ bh1,
                                                     const float* __restrict__ gh1,
                                                     const float* __restrict__ beh1,
                                                     const float* __restrict__ W,
                                                     float* __restrict__ part) {
  __shared__ float sx[8 * 128];
  __shared__ float red[4][8][64];
  int t = threadIdx.x;
  int og = blockIdx.x & 7;
  int ks = blockIdx.x >> 3;
  int k0 = ks * 128;
  if (t < 128) {
    int c = k0 + t;
    float bs = bh1[c];
    float v[8]; double s = 0.0;
#pragma unroll
    for (int b = 0; b < 8; ++b) {
      v[b] = fmaxf(funkey(y1k[b * 1024 + c]) + bs, 0.f);
      s += (double)v[b];
    }
    double m = s / 8.0, q = 0.0;
#pragma unroll
    for (int b = 0; b < 8; ++b) { double d = (double)v[b] - m; q += d * d; }
    q /= 8.0;
    double inv = 1.0 / sqrt(q + 1e-5);
    double sg = (double)gh1[c] * inv;
#pragma unroll
    for (int b = 0; b < 8; ++b)
      sx[b * 128 + t] = (float)(((double)v[b] - m) * sg + (double)beh1[c]);
  }
  __syncthreads();
  int o = og * 64 + (t & 63);
  int kq = t >> 6;
  float acc[8];
#pragma unroll
  for (int b = 0; b < 8; ++b) acc[b] = 0.f;
  for (int i = kq * 32; i < kq * 32 + 32; ++i) {
    float w = W[(size_t)(k0 + i) * 512 + o];
#pragma unroll
    for (int b = 0; b < 8; ++b) acc[b] += sx[b * 128 + i] * w;
  }
#pragma unroll
  for (int b = 0; b < 8; ++b) red[kq][b][t & 63] = acc[b];
  __syncthreads();
  if (kq == 0) {
#pragma unroll
    for (int b = 0; b < 8; ++b) {
      float s = ((red[0][b][t] + red[1][b][t]) + red[2][b][t]) + red[3][b][t];
      part[(size_t)(ks * 8 + b) * 512 + o] = s;
    }
  }
}

// head GEMM layer 2 (512->265) with FUSED chunk-sum+bias+relu+BN staging.
__global__ __launch_bounds__(256) void hgemm2_kernel(const float* __restrict__ part,
                                                     const float* __restrict__ bh2,
                                                     const float* __restrict__ gh2,
                                                     const float* __restrict__ beh2,
                                                     const float* __restrict__ W,
                                                     float* __restrict__ part2) {
  __shared__ float sx[8 * 64];
  __shared__ float red[4][8][64];
  int t = threadIdx.x;
  int og = blockIdx.x % 5;
  int ks = blockIdx.x / 5;
  int k0 = ks * 64;
  if (t < 64) {
    int c = k0 + t;
    float bs = bh2[c];
    float v[8]; double s = 0.0;
#pragma unroll
    for (int b = 0; b < 8; ++b) {
      float p = 0.f;
#pragma unroll
      for (int c2 = 0; c2 < 8; ++c2) p += part[(size_t)(c2 * 8 + b) * 512 + c];
      v[b] = fmaxf(p + bs, 0.f);
      s += (double)v[b];
    }
    double m = s / 8.0, q = 0.0;
#pragma unroll
    for (int b = 0; b < 8; ++b) { double d = (double)v[b] - m; q += d * d; }
    q /= 8.0;
    double inv = 1.0 / sqrt(q + 1e-5);
    double sg = (double)gh2[c] * inv;
#pragma unroll
    for (int b = 0; b < 8; ++b)
      sx[b * 64 + t] = (float)(((double)v[b] - m) * sg + (double)beh2[c]);
  }
  __syncthreads();
  int o = og * 64 + (t & 63);
  int kq = t >> 6;
  float acc[8];
#pragma unroll
  for (int b = 0; b < 8; ++b) acc[b] = 0.f;
  if (o < 265) {
    for (int i = kq * 16; i < kq * 16 + 16; ++i) {
      float w = W[(size_t)(k0 + i) * 265 + o];
#pragma unroll
      for (int b = 0; b < 8; ++b) acc[b] += sx[b * 64 + i] * w;
    }
  }
#pragma unroll
  for (int b = 0; b < 8; ++b) red[kq][b][t & 63] = acc[b];
  __syncthreads();
  if (kq == 0 && o < 265) {
#pragma unroll
    for (int b = 0; b < 8; ++b) {
      float s = ((red[0][b][t] + red[1][b][t]) + red[2][b][t]) + red[3][b][t];
      part2[(size_t)(ks * 8 + b) * 512 + o] = s;
    }
  }
}

// final: fused y3 reduce+BN, then [8,265]@[265,40]+b and log_softmax
__global__ __launch_bounds__(384) void logits_kernel(const float* __restrict__ part2,
                                                     const float* __restrict__ bh3,
                                                     const float* __restrict__ gh3,
                                                     const float* __restrict__ beh3,
                                                     const float* __restrict__ W,
                                                     const float* __restrict__ bias,
                                                     float* __restrict__ out) {
  __shared__ float sy[8 * 265];
  __shared__ float slog[320];
  __shared__ float sm[8], sl[8];
  int t = threadIdx.x;
  if (t < 265) {
    float bs = bh3[t];
    float v[8]; double s = 0.0;
#pragma unroll
    for (int b = 0; b < 8; ++b) {
      float p = 0.f;
#pragma unroll
      for (int c2 = 0; c2 < 8; ++c2) p += part2[(size_t)(c2 * 8 + b) * 512 + t];
      v[b] = fmaxf(p + bs, 0.f);
      s += (double)v[b];
    }
    double m = s / 8.0, q = 0.0;
#pragma unroll
    for (int b = 0; b < 8; ++b) { double d = (double)v[b] - m; q += d * d; }
    q /= 8.0;
    double inv = 1.0 / sqrt(q + 1e-5);
    double sg = (double)gh3[t] * inv;
#pragma unroll
    for (int b = 0; b < 8; ++b)
      sy[b * 265 + t] = (float)(((double)v[b] - m) * sg + (double)beh3[t]);
  }
  __syncthreads();
  if (t < 320) {
    int b = t / 40, o = t % 40;
    float acc = 0.f;
    for (int i = 0; i < 265; ++i) acc += sy[b * 265 + i] * W[i * 40 + o];
    slog[t] = acc + bias[o];
  }
  __syncthreads();
  if (t < 8) {
    float m = slog[t * 40];
    for (int o = 1; o < 40; ++o) m = fmaxf(m, slog[t * 40 + o]);
    float s = 0.f;
    for (int o = 0; o < 40; ++o) s += expf(slog[t * 40 + o] - m);
    sm[t] = m; sl[t] = logf(s);
  }
  __syncthreads();
  if (t < 320) {
    int b = t / 40;
    out[t] = slog[t] - sm[b] - sl[b];
  }
}

// ---------------- launcher ----------------
extern "C" void kernel_launch(void* const* d_in, const int* in_sizes, int n_in,
                              void* d_out, int out_size, void* d_ws, size_t ws_size,
                              hipStream_t stream) {
  (void)in_sizes; (void)n_in; (void)out_size; (void)ws_size;
  const float* pos  = (const float*)d_in[0];
  const float* w11  = (const float*)d_in[1];
  const float* b11  = (const float*)d_in[2];
  const float* g11  = (const float*)d_in[3];
  const float* be11 = (const float*)d_in[4];
  const float* w12  = (const float*)d_in[5];
  const float* b12  = (const float*)d_in[6];
  const float* g12  = (const float*)d_in[7];
  const float* be12 = (const float*)d_in[8];
  const float* w13  = (const float*)d_in[9];
  const float* b13  = (const float*)d_in[10];
  const float* g13  = (const float*)d_in[11];
  const float* be13 = (const float*)d_in[12];
  const float* w21  = (const float*)d_in[13];
  const float* b21  = (const float*)d_in[14];
  const float* g21  = (const float*)d_in[15];
  const float* be21 = (const float*)d_in[16];
  const float* wh1  = (const float*)d_in[17];
  const float* bh1  = (const float*)d_in[18];
  const float* gh1  = (const float*)d_in[19];
  const float* beh1 = (const float*)d_in[20];
  const float* wh2  = (const float*)d_in[21];
  const float* bh2  = (const float*)d_in[22];
  const float* gh2  = (const float*)d_in[23];
  const float* beh2 = (const float*)d_in[24];
  const float* wh3  = (const float*)d_in[25];
  const float* bh3  = (const float*)d_in[26];
  const float* gh3  = (const float*)d_in[27];
  const float* beh3 = (const float*)d_in[28];
  const float* wh4  = (const float*)d_in[29];
  const float* bh4  = (const float*)d_in[30];

  char* ws = (char*)d_ws;
  int*    idx   = (int*)(ws + 0);                 // 1,310,720 B
  float*  loc   = (float*)(ws + 1310720);         // 3,932,160 B
  float*  V     = (float*)(ws + 5242880);         //   589,824 B
  float*  h     = (float*)(ws + 5832704);         // 83,886,080 B (fp32, in-place)
  u16*    wt    = (u16*)(ws + 5832704);           // 49,152 B (overlays h AFTER f3d)
  double* s4b   = (double*)(ws + 5898240);        // 131,072 B (h + 64KB)
  float*  hpart = (float*)(ws + 6881280);         // 131,072 B (h + 1MB)
  float*  hpart2= (float*)(ws + 7012352);         // 131,072 B
  float*  f3d   = (float*)(ws + 89718784);        // 12,582,912 B
  double* sbkt  = (double*)(ws + 89718784);       // 196,608 B (BN1-3 buckets,
                                                  //   consumed before f3d writes)
  u16*    wsp   = (u16*)(ws + 89718784 + 196608); // 32,768 B (split W12/W13,
                                                  //   consumed before f3d writes)
  float*  fdd2T = (float*)(ws + 102301696);       //  8,388,608 B ([128][16384])
  u32*    y1k   = (u32*)(ws + 110690304);         //     32,768 B
  float*  param = (float*)(ws + 110785856);       // 640 floats
  float*  out   = (float*)d_out;

  double* sbL1 = sbkt;
  double* sbL2 = sbkt + 8192;
  double* sbL3 = sbkt + 16384;

  init_kernel<<<96, 256, 0, stream>>>(sbkt, y1k, w12, w13, wsp);
  knn_kernel<<<4096, 256, 0, stream>>>(pos, idx);
  prep_kernel<<<256, 64, 0, stream>>>(pos, idx, loc, V);

  l1_kernel<<<1280, 256, 0, stream>>>(loc, w11, b11, h, sbL1);
  finalizeB_kernel<<<1, 64, 0, stream>>>(sbL1, g11, be11, param);

  l23_kernel<<<2560, 256, 0, stream>>>(h, param, wsp, wsp + 4096, b12, h, sbL2);
  finalizeB_kernel<<<1, 64, 0, stream>>>(sbL2, g12, be12, param + 128);

  l23_kernel<<<2560, 256, 0, stream>>>(h, param + 128, wsp + 8192, wsp + 12288, b13, h, sbL3);
  finalizeB_kernel<<<1, 64, 0, stream>>>(sbL3, g13, be13, param + 256);

  f3d_kernel<<<4096, 256, 0, stream>>>(h, param + 256, loc, f3d);
  // h is dead now; wt + s4b + hpart overlay it
  wtcvt_kernel<<<96, 256, 0, stream>>>(w21, wt, s4b);
  dd2_kernel<<<4096, 512, 0, stream>>>(f3d, V, idx, wt, b21, fdd2T, s4b);
  finalize64_kernel<<<1, 128, 0, stream>>>(s4b, g21, be21, param + 384);

  y1_kernel<<<1024, 256, 0, stream>>>(fdd2T, param + 384, wh1, y1k);

  hgemm1_kernel<<<64, 256, 0, stream>>>(y1k, bh1, gh1, beh1, wh2, hpart);
  hgemm2_kernel<<<40, 256, 0, stream>>>(hpart, bh2, gh2, beh2, wh3, hpart2);
  logits_kernel<<<1, 384, 0, stream>>>(hpart2, bh3, gh3, beh3, wh4, bh4, out);
}